// Round 10
// baseline (111.412 us; speedup 1.0000x reference)
//
#include <hip/hip_runtime.h>

// Chamfer via MFMA half-distance matrix, v6: occupancy + L2 locality.
// R9 post-mortem: AGPR-mov theory confirmed (VALUBusy 84->39%, VGPR 80),
// but wall stuck at 48.4us with MfmaUtil 27 / VALU 39 / Occ 18% -- pipe sum
// ~16us vs 48 measured => latency-bound at 2 waves/SIMD (512 blocks), with
// FETCH 17.3MB showing the 4MB fragment array re-fetched ~4x from HBM.
// R7's "waves don't help" was the VALU-saturated regime; now pipes are idle.
// R10: (1) DSPLIT=4 -> 1024 blocks = 4 waves/SIMD; (2) launch_bounds(256,4)
// (128-VGPR budget, no AGPR fallback -- tell: VGPR ~80-110); (3) bijective
// XCD-panel swizzle: all 16 qb-siblings of a (b,dir,ds) fragment panel get
// the same lin&7 -> same XCD -> 64KB panel L2-resident (FETCH 17->~6MB).
//
// Math (R5-R9 verified, absmax 0.0): h = 0.5|p|^2 + 0.5|t|^2 - p.t = d/2
// via K=16 of v_mfma_f32_32x32x16_bf16 with bf16 hi/lo split:
//   A(p): half0 [xh xh xl yh yh yl zh zh]  half1 [zl ph pl 1 1 0 0 0]
//   B(t): half0 [nxh nxl nxh nyh nyl nyh nzh nzl] half1 [nzh 1 1 hh hl 0 0 0]
// C layout (m74/m101): col=lane&31, row=(reg&3)+8*(reg>>2)+4*(lane>>5).
// Both directions run as row-min MFMA passes (dir1 swaps A/B roles).

typedef float f32x16 __attribute__((ext_vector_type(16)));
typedef short bf16x8 __attribute__((ext_vector_type(8)));

constexpr int BATCH  = 8;
constexpr int NPTS   = 8192;
constexpr int BLOCK  = 256;            // 4 waves
constexpr int QTILE  = 512;            // A-points per block (128 per wave)
constexpr int NAF    = 4;              // A-frags per wave
constexpr int QB     = NPTS / QTILE;   // 16 A-blocks per direction
constexpr int DSPLIT = 4;              // db split per direction
constexpr int DBR    = NPTS / DSPLIT;  // 2048 db points per block
constexpr int CH     = 256;            // db points per LDS chunk
constexpr int NCH    = DBR / CH;       // 8 chunks
constexpr int NBLK   = QB * BATCH * 2 * DSPLIT;   // 1024

// workspace: fragT [B][NPTS][2] uint4 (2MB) | fragS same (2MB)
//            | mins [2][B][NPTS] u32 (512KB)
constexpr size_t FRAG_N = (size_t)BATCH * NPTS * 2;   // uint4s per array
constexpr size_t SM_N   = (size_t)BATCH * NPTS;       // u32 per direction

static __device__ __forceinline__ float fmin3(float a, float b, float c) {
    return fminf(fminf(a, b), c);   // v_min3_f32
}
static __device__ __forceinline__ unsigned short bf16h(float f) {
    unsigned int u = __float_as_uint(f);
    u += 0x7fffu + ((u >> 16) & 1u);           // RNE
    return (unsigned short)(u >> 16);
}
static __device__ __forceinline__ float bf16tof(unsigned short h) {
    return __uint_as_float(((unsigned int)h) << 16);
}
static __device__ __forceinline__ unsigned int pack2(unsigned short a, unsigned short b) {
    return (unsigned int)a | ((unsigned int)b << 16);
}

static __device__ __forceinline__ void make_bfrag(float px, float py, float pz,
                                                  uint4& p0, uint4& p1) {
    const unsigned short one = bf16h(1.0f);
    float nx = -px, ny = -py, nz = -pz;
    float ht = 0.5f * fmaf(px, px, fmaf(py, py, pz * pz));
    unsigned short nxh = bf16h(nx), nxl = bf16h(nx - bf16tof(nxh));
    unsigned short nyh = bf16h(ny), nyl = bf16h(ny - bf16tof(nyh));
    unsigned short nzh = bf16h(nz), nzl = bf16h(nz - bf16tof(nzh));
    unsigned short hh = bf16h(ht),  hl = bf16h(ht - bf16tof(hh));
    p0 = make_uint4(pack2(nxh, nxl), pack2(nxh, nyh),
                    pack2(nyl, nyh), pack2(nzh, nzl));
    p1 = make_uint4(pack2(nzh, one), pack2(one, hh),
                    pack2(hl, 0), 0u);
}

// ---- prep: both arrays -> B-fragments; init mins; zero out ----
__global__ __launch_bounds__(BLOCK) void chamfer_prep(
    const float* __restrict__ src, const float* __restrict__ tgt,
    uint4* __restrict__ fragS, uint4* __restrict__ fragT,
    unsigned int* __restrict__ mins, float* __restrict__ out)
{
    const int i = blockIdx.x * BLOCK + threadIdx.x;   // [0, B*NPTS)
    uint4 p0, p1;
    const float* tp = tgt + (size_t)i * 3;
    make_bfrag(tp[0], tp[1], tp[2], p0, p1);
    fragT[2 * i + 0] = p0;
    fragT[2 * i + 1] = p1;
    const float* sp = src + (size_t)i * 3;
    make_bfrag(sp[0], sp[1], sp[2], p0, p1);
    fragS[2 * i + 0] = p0;
    fragS[2 * i + 1] = p1;
    mins[i]        = 0x7f7f7f7fu;
    mins[SM_N + i] = 0x7f7f7f7fu;
    if (i < BATCH) out[i] = 0.0f;
}

__global__ __launch_bounds__(BLOCK, 4) void chamfer_nn(
    const float* __restrict__ src, const float* __restrict__ tgt,
    const uint4* __restrict__ fragS, const uint4* __restrict__ fragT,
    unsigned int* __restrict__ mins)
{
    __shared__ uint4 Bfr0[CH], Bfr1[CH];   // staged B frags (k-half 0 / 1)

    const int tid  = threadIdx.x;
    const int lane = tid & 63;
    const int w    = tid >> 6;
    const int half = lane >> 5;
    const int l31  = lane & 31;

    // ---- XCD-panel swizzle (bijective on [0,1024)) ----
    // lin = (((p>>3)<<4)|qb)<<3 | (p&7): the 16 qb-siblings of panel p
    // share lin&7 -> same XCD under mod-8 round-robin dispatch.
    const int lin  = blockIdx.x;
    const int rest = lin >> 3;                        // [0,128)
    const int qb   = rest & 15;                       // [0,16)
    const int p    = ((rest >> 4) << 3) | (lin & 7);  // panel [0,64)
    const int b    = p & 7;
    const int z    = p >> 3;                          // [0,8)
    const int dir  = z >> 2;   // 0: A=src,B=tgt ; 1: swapped
    const int ds   = z & 3;

    const float* P  = dir ? tgt : src;      // A-side raw points
    const uint4* FB = dir ? fragS : fragT;  // B-side fragments

    // ---- build NAF A-fragments (A-points qbase + g*32 + l31) ----
    const unsigned short one = bf16h(1.0f);
    bf16x8 af[NAF];
#pragma unroll
    for (int g = 0; g < NAF; g++) {
        const int q = qb * QTILE + w * (32 * NAF) + g * 32 + l31;
        const float* qp = P + ((size_t)b * NPTS + q) * 3;
        float qx = qp[0], qy = qp[1], qz = qp[2];
        float hq = 0.5f * fmaf(qx, qx, fmaf(qy, qy, qz * qz));
        unsigned short xh = bf16h(qx), xl = bf16h(qx - bf16tof(xh));
        unsigned short yh = bf16h(qy), yl = bf16h(qy - bf16tof(yh));
        unsigned short zh = bf16h(qz), zl = bf16h(qz - bf16tof(zh));
        unsigned short qh = bf16h(hq), ql = bf16h(hq - bf16tof(qh));
        bf16x8 a;
        if (half == 0) {
            a[0] = (short)xh; a[1] = (short)xh; a[2] = (short)xl;
            a[3] = (short)yh; a[4] = (short)yh; a[5] = (short)yl;
            a[6] = (short)zh; a[7] = (short)zh;
        } else {
            a[0] = (short)zl; a[1] = (short)qh; a[2] = (short)ql;
            a[3] = (short)one; a[4] = (short)one;
            a[5] = 0; a[6] = 0; a[7] = 0;
        }
        af[g] = a;
    }

    float rmn[NAF][16];
#pragma unroll
    for (int g = 0; g < NAF; g++)
#pragma unroll
        for (int r = 0; r < 16; r++) rmn[g][r] = 3.4e38f;
    const f32x16 zz = {};   // persistent zero VGPRs, C input for all MFMAs
    const uint4* Bh = half ? Bfr1 : Bfr0;

    const uint4* fb = FB + ((size_t)b * NPTS + (size_t)ds * DBR) * 2;

    // reg-stage chunk 0 (T14: issue early, write after barrier)
    uint4 r0 = fb[2 * tid + 0], r1 = fb[2 * tid + 1];

    for (int c = 0; c < NCH; ++c) {
        __syncthreads();                     // prev chunk's LDS reads done
        Bfr0[tid] = r0;
        Bfr1[tid] = r1;
        __syncthreads();                     // staging visible
        if (c + 1 < NCH) {                   // prefetch next chunk into regs
            r0 = fb[2 * ((c + 1) * CH + tid) + 0];
            r1 = fb[2 * ((c + 1) * CH + tid) + 1];
        }

#pragma unroll
        for (int tp = 0; tp < CH / 64; ++tp) {   // 4 tile-pairs of 64 db pts
            const int t0 = tp * 2, t1 = tp * 2 + 1;
            bf16x8 b0 = *reinterpret_cast<const bf16x8*>(&Bh[t0 * 32 + l31]);
            bf16x8 b1 = *reinterpret_cast<const bf16x8*>(&Bh[t1 * 32 + l31]);
#pragma unroll
            for (int g = 0; g < NAF; g++) {
                f32x16 aa = __builtin_amdgcn_mfma_f32_32x32x16_bf16(af[g], b0, zz, 0, 0, 0);
                f32x16 ab = __builtin_amdgcn_mfma_f32_32x32x16_bf16(af[g], b1, zz, 0, 0, 0);
#pragma unroll
                for (int r = 0; r < 16; r++)
                    rmn[g][r] = fmin3(rmn[g][r], aa[r], ab[r]);   // row-min
            }
        }
    }

    // ---- epilogue: fold cols 32->1 in-wave, global atomicMin merge ----
    unsigned int* M = mins + ((size_t)dir * BATCH + b) * NPTS;
    const int qbase = qb * QTILE + w * (32 * NAF);
#pragma unroll
    for (int g = 0; g < NAF; g++) {
#pragma unroll
        for (int r = 0; r < 16; r++) {
            float a = rmn[g][r];
#pragma unroll
            for (int off = 16; off > 0; off >>= 1)
                a = fminf(a, __shfl_xor(a, off, 64));
            if (l31 == 0) {   // lanes 0 (half0 row) and 32 (half1 row)
                const int row = (r & 3) + 8 * (r >> 2) + 4 * half;
                atomicMin(&M[qbase + g * 32 + row],
                          __float_as_uint(fmaxf(a, 0.0f)));
            }
        }
    }
}

// ---- final: sum mins[2][B][NPTS] (512KB), atomicAdd into out ----
__global__ __launch_bounds__(BLOCK) void chamfer_final(
    const unsigned int* __restrict__ mins, float* __restrict__ out)
{
    const int seg = blockIdx.x;   // 4 segments of 2048
    const int b   = blockIdx.y;
    const int tid = threadIdx.x;
    float acc = 0.0f;
#pragma unroll
    for (int k = 0; k < 8; k++) {
        const size_t i = (size_t)b * NPTS + seg * 2048 + k * BLOCK + tid;
        acc += __uint_as_float(mins[i]) + __uint_as_float(mins[SM_N + i]);
    }
    for (int off = 32; off > 0; off >>= 1) acc += __shfl_down(acc, off, 64);
    __shared__ float wsum[4];
    if ((tid & 63) == 0) wsum[tid >> 6] = acc;
    __syncthreads();
    if (tid == 0)   // stored values are half-distances: d = 2h
        atomicAdd(&out[b],
                  (wsum[0] + wsum[1] + wsum[2] + wsum[3]) * (2.0f / (float)NPTS));
}

extern "C" void kernel_launch(void* const* d_in, const int* in_sizes, int n_in,
                              void* d_out, int out_size, void* d_ws, size_t ws_size,
                              hipStream_t stream) {
    const float* src = (const float*)d_in[0];  // [B, N, 3]
    const float* tgt = (const float*)d_in[1];  // [B, M, 3]
    float* out = (float*)d_out;                // [B]

    uint4* fragT        = (uint4*)d_ws;                     // 2 MB
    uint4* fragS        = fragT + FRAG_N;                   // 2 MB
    unsigned int* mins  = (unsigned int*)(fragS + FRAG_N);  // 512 KB

    chamfer_prep<<<BATCH * NPTS / BLOCK, BLOCK, 0, stream>>>(
        src, tgt, fragS, fragT, mins, out);
    chamfer_nn<<<NBLK, BLOCK, 0, stream>>>(
        src, tgt, fragS, fragT, mins);
    chamfer_final<<<dim3(4, BATCH), BLOCK, 0, stream>>>(mins, out);
}

// Round 11
// 109.098 us; speedup vs baseline: 1.0212x; 1.0212x over previous
//
#include <hip/hip_runtime.h>

// Chamfer via MFMA half-distance matrix, v7: R10 spill fix.
// R10 post-mortem: __launch_bounds__(256,4) halved the unified reg budget
// to 128; kernel needs ~80 VGPR + 64 accumulator floats -> allocator
// SPILLED rmn to scratch (WRITE_SIZE 4->21.5MB, VGPR_Count 64, dur +10us).
// The swizzle itself worked (FETCH 17.3->9.6MB) and occupancy rose 18->31%.
// R9 tell: VGPR=80 allows 6 waves/SIMD; the R9 limiter was grid (512
// blocks = 2/CU), not registers. R11 = R9 codegen + R10 grid:
// __launch_bounds__(256,2) (no spill, VGPR ~80) + DSPLIT=4 (1024 blocks =
// 4 waves/SIMD) + XCD-panel swizzle. Single-variable vs R10.
//
// Math (R5-R10 verified, absmax 0.0): h = 0.5|p|^2 + 0.5|t|^2 - p.t = d/2
// via K=16 of v_mfma_f32_32x32x16_bf16 with bf16 hi/lo split:
//   A(p): half0 [xh xh xl yh yh yl zh zh]  half1 [zl ph pl 1 1 0 0 0]
//   B(t): half0 [nxh nxl nxh nyh nyl nyh nzh nzl] half1 [nzh 1 1 hh hl 0 0 0]
// C layout (m74/m101): col=lane&31, row=(reg&3)+8*(reg>>2)+4*(lane>>5).
// Both directions run as row-min MFMA passes (dir1 swaps A/B roles).

typedef float f32x16 __attribute__((ext_vector_type(16)));
typedef short bf16x8 __attribute__((ext_vector_type(8)));

constexpr int BATCH  = 8;
constexpr int NPTS   = 8192;
constexpr int BLOCK  = 256;            // 4 waves
constexpr int QTILE  = 512;            // A-points per block (128 per wave)
constexpr int NAF    = 4;              // A-frags per wave
constexpr int QB     = NPTS / QTILE;   // 16 A-blocks per direction
constexpr int DSPLIT = 4;              // db split per direction
constexpr int DBR    = NPTS / DSPLIT;  // 2048 db points per block
constexpr int CH     = 256;            // db points per LDS chunk
constexpr int NCH    = DBR / CH;       // 8 chunks
constexpr int NBLK   = QB * BATCH * 2 * DSPLIT;   // 1024

// workspace: fragT [B][NPTS][2] uint4 (2MB) | fragS same (2MB)
//            | mins [2][B][NPTS] u32 (512KB)
constexpr size_t FRAG_N = (size_t)BATCH * NPTS * 2;   // uint4s per array
constexpr size_t SM_N   = (size_t)BATCH * NPTS;       // u32 per direction

static __device__ __forceinline__ float fmin3(float a, float b, float c) {
    return fminf(fminf(a, b), c);   // v_min3_f32
}
static __device__ __forceinline__ unsigned short bf16h(float f) {
    unsigned int u = __float_as_uint(f);
    u += 0x7fffu + ((u >> 16) & 1u);           // RNE
    return (unsigned short)(u >> 16);
}
static __device__ __forceinline__ float bf16tof(unsigned short h) {
    return __uint_as_float(((unsigned int)h) << 16);
}
static __device__ __forceinline__ unsigned int pack2(unsigned short a, unsigned short b) {
    return (unsigned int)a | ((unsigned int)b << 16);
}

static __device__ __forceinline__ void make_bfrag(float px, float py, float pz,
                                                  uint4& p0, uint4& p1) {
    const unsigned short one = bf16h(1.0f);
    float nx = -px, ny = -py, nz = -pz;
    float ht = 0.5f * fmaf(px, px, fmaf(py, py, pz * pz));
    unsigned short nxh = bf16h(nx), nxl = bf16h(nx - bf16tof(nxh));
    unsigned short nyh = bf16h(ny), nyl = bf16h(ny - bf16tof(nyh));
    unsigned short nzh = bf16h(nz), nzl = bf16h(nz - bf16tof(nzh));
    unsigned short hh = bf16h(ht),  hl = bf16h(ht - bf16tof(hh));
    p0 = make_uint4(pack2(nxh, nxl), pack2(nxh, nyh),
                    pack2(nyl, nyh), pack2(nzh, nzl));
    p1 = make_uint4(pack2(nzh, one), pack2(one, hh),
                    pack2(hl, 0), 0u);
}

// ---- prep: both arrays -> B-fragments; init mins; zero out ----
__global__ __launch_bounds__(BLOCK) void chamfer_prep(
    const float* __restrict__ src, const float* __restrict__ tgt,
    uint4* __restrict__ fragS, uint4* __restrict__ fragT,
    unsigned int* __restrict__ mins, float* __restrict__ out)
{
    const int i = blockIdx.x * BLOCK + threadIdx.x;   // [0, B*NPTS)
    uint4 p0, p1;
    const float* tp = tgt + (size_t)i * 3;
    make_bfrag(tp[0], tp[1], tp[2], p0, p1);
    fragT[2 * i + 0] = p0;
    fragT[2 * i + 1] = p1;
    const float* sp = src + (size_t)i * 3;
    make_bfrag(sp[0], sp[1], sp[2], p0, p1);
    fragS[2 * i + 0] = p0;
    fragS[2 * i + 1] = p1;
    mins[i]        = 0x7f7f7f7fu;
    mins[SM_N + i] = 0x7f7f7f7fu;
    if (i < BATCH) out[i] = 0.0f;
}

__global__ __launch_bounds__(BLOCK, 2) void chamfer_nn(
    const float* __restrict__ src, const float* __restrict__ tgt,
    const uint4* __restrict__ fragS, const uint4* __restrict__ fragT,
    unsigned int* __restrict__ mins)
{
    __shared__ uint4 Bfr0[CH], Bfr1[CH];   // staged B frags (k-half 0 / 1)

    const int tid  = threadIdx.x;
    const int lane = tid & 63;
    const int w    = tid >> 6;
    const int half = lane >> 5;
    const int l31  = lane & 31;

    // ---- XCD-panel swizzle (bijective on [0,1024)) ----
    // The 16 qb-siblings of a (b,dir,ds) fragment panel share lin&7 ->
    // same XCD under mod-8 round-robin dispatch -> 64KB panel L2-resident.
    const int lin  = blockIdx.x;
    const int rest = lin >> 3;                        // [0,128)
    const int qb   = rest & 15;                       // [0,16)
    const int p    = ((rest >> 4) << 3) | (lin & 7);  // panel [0,64)
    const int b    = p & 7;
    const int z    = p >> 3;                          // [0,8)
    const int dir  = z >> 2;   // 0: A=src,B=tgt ; 1: swapped
    const int ds   = z & 3;

    const float* P  = dir ? tgt : src;      // A-side raw points
    const uint4* FB = dir ? fragS : fragT;  // B-side fragments

    // ---- build NAF A-fragments (A-points qbase + g*32 + l31) ----
    const unsigned short one = bf16h(1.0f);
    bf16x8 af[NAF];
#pragma unroll
    for (int g = 0; g < NAF; g++) {
        const int q = qb * QTILE + w * (32 * NAF) + g * 32 + l31;
        const float* qp = P + ((size_t)b * NPTS + q) * 3;
        float qx = qp[0], qy = qp[1], qz = qp[2];
        float hq = 0.5f * fmaf(qx, qx, fmaf(qy, qy, qz * qz));
        unsigned short xh = bf16h(qx), xl = bf16h(qx - bf16tof(xh));
        unsigned short yh = bf16h(qy), yl = bf16h(qy - bf16tof(yh));
        unsigned short zh = bf16h(qz), zl = bf16h(qz - bf16tof(zh));
        unsigned short qh = bf16h(hq), ql = bf16h(hq - bf16tof(qh));
        bf16x8 a;
        if (half == 0) {
            a[0] = (short)xh; a[1] = (short)xh; a[2] = (short)xl;
            a[3] = (short)yh; a[4] = (short)yh; a[5] = (short)yl;
            a[6] = (short)zh; a[7] = (short)zh;
        } else {
            a[0] = (short)zl; a[1] = (short)qh; a[2] = (short)ql;
            a[3] = (short)one; a[4] = (short)one;
            a[5] = 0; a[6] = 0; a[7] = 0;
        }
        af[g] = a;
    }

    float rmn[NAF][16];
#pragma unroll
    for (int g = 0; g < NAF; g++)
#pragma unroll
        for (int r = 0; r < 16; r++) rmn[g][r] = 3.4e38f;
    const f32x16 zz = {};   // persistent zero VGPRs, C input for all MFMAs
    const uint4* Bh = half ? Bfr1 : Bfr0;

    const uint4* fb = FB + ((size_t)b * NPTS + (size_t)ds * DBR) * 2;

    // reg-stage chunk 0 (T14: issue early, write after barrier)
    uint4 r0 = fb[2 * tid + 0], r1 = fb[2 * tid + 1];

    for (int c = 0; c < NCH; ++c) {
        __syncthreads();                     // prev chunk's LDS reads done
        Bfr0[tid] = r0;
        Bfr1[tid] = r1;
        __syncthreads();                     // staging visible
        if (c + 1 < NCH) {                   // prefetch next chunk into regs
            r0 = fb[2 * ((c + 1) * CH + tid) + 0];
            r1 = fb[2 * ((c + 1) * CH + tid) + 1];
        }

#pragma unroll
        for (int tp = 0; tp < CH / 64; ++tp) {   // 4 tile-pairs of 64 db pts
            const int t0 = tp * 2, t1 = tp * 2 + 1;
            bf16x8 b0 = *reinterpret_cast<const bf16x8*>(&Bh[t0 * 32 + l31]);
            bf16x8 b1 = *reinterpret_cast<const bf16x8*>(&Bh[t1 * 32 + l31]);
#pragma unroll
            for (int g = 0; g < NAF; g++) {
                f32x16 aa = __builtin_amdgcn_mfma_f32_32x32x16_bf16(af[g], b0, zz, 0, 0, 0);
                f32x16 ab = __builtin_amdgcn_mfma_f32_32x32x16_bf16(af[g], b1, zz, 0, 0, 0);
#pragma unroll
                for (int r = 0; r < 16; r++)
                    rmn[g][r] = fmin3(rmn[g][r], aa[r], ab[r]);   // row-min
            }
        }
    }

    // ---- epilogue: fold cols 32->1 in-wave, global atomicMin merge ----
    unsigned int* M = mins + ((size_t)dir * BATCH + b) * NPTS;
    const int qbase = qb * QTILE + w * (32 * NAF);
#pragma unroll
    for (int g = 0; g < NAF; g++) {
#pragma unroll
        for (int r = 0; r < 16; r++) {
            float a = rmn[g][r];
#pragma unroll
            for (int off = 16; off > 0; off >>= 1)
                a = fminf(a, __shfl_xor(a, off, 64));
            if (l31 == 0) {   // lanes 0 (half0 row) and 32 (half1 row)
                const int row = (r & 3) + 8 * (r >> 2) + 4 * half;
                atomicMin(&M[qbase + g * 32 + row],
                          __float_as_uint(fmaxf(a, 0.0f)));
            }
        }
    }
}

// ---- final: sum mins[2][B][NPTS] (512KB), atomicAdd into out ----
__global__ __launch_bounds__(BLOCK) void chamfer_final(
    const unsigned int* __restrict__ mins, float* __restrict__ out)
{
    const int seg = blockIdx.x;   // 4 segments of 2048
    const int b   = blockIdx.y;
    const int tid = threadIdx.x;
    float acc = 0.0f;
#pragma unroll
    for (int k = 0; k < 8; k++) {
        const size_t i = (size_t)b * NPTS + seg * 2048 + k * BLOCK + tid;
        acc += __uint_as_float(mins[i]) + __uint_as_float(mins[SM_N + i]);
    }
    for (int off = 32; off > 0; off >>= 1) acc += __shfl_down(acc, off, 64);
    __shared__ float wsum[4];
    if ((tid & 63) == 0) wsum[tid >> 6] = acc;
    __syncthreads();
    if (tid == 0)   // stored values are half-distances: d = 2h
        atomicAdd(&out[b],
                  (wsum[0] + wsum[1] + wsum[2] + wsum[3]) * (2.0f / (float)NPTS));
}

extern "C" void kernel_launch(void* const* d_in, const int* in_sizes, int n_in,
                              void* d_out, int out_size, void* d_ws, size_t ws_size,
                              hipStream_t stream) {
    const float* src = (const float*)d_in[0];  // [B, N, 3]
    const float* tgt = (const float*)d_in[1];  // [B, M, 3]
    float* out = (float*)d_out;                // [B]

    uint4* fragT        = (uint4*)d_ws;                     // 2 MB
    uint4* fragS        = fragT + FRAG_N;                   // 2 MB
    unsigned int* mins  = (unsigned int*)(fragS + FRAG_N);  // 512 KB

    chamfer_prep<<<BATCH * NPTS / BLOCK, BLOCK, 0, stream>>>(
        src, tgt, fragS, fragT, mins, out);
    chamfer_nn<<<NBLK, BLOCK, 0, stream>>>(
        src, tgt, fragS, fragT, mins);
    chamfer_final<<<dim3(4, BATCH), BLOCK, 0, stream>>>(mins, out);
}

// Round 12
// 101.651 us; speedup vs baseline: 1.0960x; 1.0733x over previous
//
#include <hip/hip_runtime.h>

// Chamfer via MFMA half-distance matrix, v8: force MFMA-result ILP.
// R11 post-mortem: swizzle validated (FETCH 17.3->2.9MB, staging = L2 hits),
// no spill (VGPR 80, WRITE 8MB=atomics), yet dur 55.6 > R9's 48.4 with all
// pipes idle (Mfma 24 / VALU 40 / Occ 23). Memory latency is ruled out. The
// tell is VGPR_Count=80 under a 256 budget: the compiler keeps only ~2
// f32x16 MFMA results live and serializes mfma -> ~30cyc result latency ->
// 16 min3 -> reg reuse. That serialization, not occupancy, has been the
// limiter since R9 (explains R7/R9/R11 invariance to wave supply).
// R12: three sched_barrier(0)-fenced regions per tile-pair:
//   (1) issue 4 MFMAs (g0,g1) into distinct named results;
//   (2) issue 4 MFMAs (g2,g3) + consume batch 1 (scheduler interleaves;
//       batch-1 results ready after batch-2 issue);
//   (3) consume batch 2.
// Peak ~128 result regs live -> expect VGPR 180-240 (TELL: >=170; WRITE
// must stay ~4MB else it spilled, R10's signature). Geometry = R9 best
// (DSPLIT=2, 512 blocks, NCH=16) + XCD-panel swizzle for 512.
//
// Math (R5-R11 verified, absmax 0.0): h = 0.5|p|^2 + 0.5|t|^2 - p.t = d/2
// via K=16 of v_mfma_f32_32x32x16_bf16 with bf16 hi/lo split:
//   A(p): half0 [xh xh xl yh yh yl zh zh]  half1 [zl ph pl 1 1 0 0 0]
//   B(t): half0 [nxh nxl nxh nyh nyl nyh nzh nzl] half1 [nzh 1 1 hh hl 0 0 0]
// C layout (m74/m101): col=lane&31, row=(reg&3)+8*(reg>>2)+4*(lane>>5).
// Both directions run as row-min MFMA passes (dir1 swaps A/B roles).

typedef float f32x16 __attribute__((ext_vector_type(16)));
typedef short bf16x8 __attribute__((ext_vector_type(8)));

constexpr int BATCH  = 8;
constexpr int NPTS   = 8192;
constexpr int BLOCK  = 256;            // 4 waves
constexpr int QTILE  = 512;            // A-points per block (128 per wave)
constexpr int NAF    = 4;              // A-frags per wave
constexpr int QB     = NPTS / QTILE;   // 16 A-blocks per direction
constexpr int DSPLIT = 2;              // db split per direction
constexpr int DBR    = NPTS / DSPLIT;  // 4096 db points per block
constexpr int CH     = 256;            // db points per LDS chunk
constexpr int NCH    = DBR / CH;       // 16 chunks
constexpr int NBLK   = QB * BATCH * 2 * DSPLIT;   // 512

// workspace: fragT [B][NPTS][2] uint4 (2MB) | fragS same (2MB)
//            | mins [2][B][NPTS] u32 (512KB)
constexpr size_t FRAG_N = (size_t)BATCH * NPTS * 2;   // uint4s per array
constexpr size_t SM_N   = (size_t)BATCH * NPTS;       // u32 per direction

static __device__ __forceinline__ float fmin3(float a, float b, float c) {
    return fminf(fminf(a, b), c);   // v_min3_f32
}
static __device__ __forceinline__ unsigned short bf16h(float f) {
    unsigned int u = __float_as_uint(f);
    u += 0x7fffu + ((u >> 16) & 1u);           // RNE
    return (unsigned short)(u >> 16);
}
static __device__ __forceinline__ float bf16tof(unsigned short h) {
    return __uint_as_float(((unsigned int)h) << 16);
}
static __device__ __forceinline__ unsigned int pack2(unsigned short a, unsigned short b) {
    return (unsigned int)a | ((unsigned int)b << 16);
}

static __device__ __forceinline__ void make_bfrag(float px, float py, float pz,
                                                  uint4& p0, uint4& p1) {
    const unsigned short one = bf16h(1.0f);
    float nx = -px, ny = -py, nz = -pz;
    float ht = 0.5f * fmaf(px, px, fmaf(py, py, pz * pz));
    unsigned short nxh = bf16h(nx), nxl = bf16h(nx - bf16tof(nxh));
    unsigned short nyh = bf16h(ny), nyl = bf16h(ny - bf16tof(nyh));
    unsigned short nzh = bf16h(nz), nzl = bf16h(nz - bf16tof(nzh));
    unsigned short hh = bf16h(ht),  hl = bf16h(ht - bf16tof(hh));
    p0 = make_uint4(pack2(nxh, nxl), pack2(nxh, nyh),
                    pack2(nyl, nyh), pack2(nzh, nzl));
    p1 = make_uint4(pack2(nzh, one), pack2(one, hh),
                    pack2(hl, 0), 0u);
}

// ---- prep: both arrays -> B-fragments; init mins; zero out ----
__global__ __launch_bounds__(BLOCK) void chamfer_prep(
    const float* __restrict__ src, const float* __restrict__ tgt,
    uint4* __restrict__ fragS, uint4* __restrict__ fragT,
    unsigned int* __restrict__ mins, float* __restrict__ out)
{
    const int i = blockIdx.x * BLOCK + threadIdx.x;   // [0, B*NPTS)
    uint4 p0, p1;
    const float* tp = tgt + (size_t)i * 3;
    make_bfrag(tp[0], tp[1], tp[2], p0, p1);
    fragT[2 * i + 0] = p0;
    fragT[2 * i + 1] = p1;
    const float* sp = src + (size_t)i * 3;
    make_bfrag(sp[0], sp[1], sp[2], p0, p1);
    fragS[2 * i + 0] = p0;
    fragS[2 * i + 1] = p1;
    mins[i]        = 0x7f7f7f7fu;
    mins[SM_N + i] = 0x7f7f7f7fu;
    if (i < BATCH) out[i] = 0.0f;
}

__global__ __launch_bounds__(BLOCK, 2) void chamfer_nn(
    const float* __restrict__ src, const float* __restrict__ tgt,
    const uint4* __restrict__ fragS, const uint4* __restrict__ fragT,
    unsigned int* __restrict__ mins)
{
    __shared__ uint4 Bfr0[CH], Bfr1[CH];   // staged B frags (k-half 0 / 1)

    const int tid  = threadIdx.x;
    const int lane = tid & 63;
    const int w    = tid >> 6;
    const int half = lane >> 5;
    const int l31  = lane & 31;

    // ---- XCD-panel swizzle (bijective on [0,512)) ----
    // The 16 qb-siblings of a (b,dir,ds) fragment panel share lin&7 ->
    // same XCD under mod-8 round-robin dispatch -> panel L2-resident.
    // (validated R10/R11: FETCH 17.3 -> 2.9 MB)
    const int lin  = blockIdx.x;
    const int rest = lin >> 3;                        // [0,64)
    const int qb   = rest & 15;                       // [0,16)
    const int p    = ((rest >> 4) << 3) | (lin & 7);  // panel [0,32)
    const int b    = p & 7;
    const int z    = p >> 3;                          // [0,4)
    const int dir  = z >> 1;   // 0: A=src,B=tgt ; 1: swapped
    const int ds   = z & 1;

    const float* P  = dir ? tgt : src;      // A-side raw points
    const uint4* FB = dir ? fragS : fragT;  // B-side fragments

    // ---- build NAF A-fragments (A-points qbase + g*32 + l31) ----
    const unsigned short one = bf16h(1.0f);
    bf16x8 af[NAF];
#pragma unroll
    for (int g = 0; g < NAF; g++) {
        const int q = qb * QTILE + w * (32 * NAF) + g * 32 + l31;
        const float* qp = P + ((size_t)b * NPTS + q) * 3;
        float qx = qp[0], qy = qp[1], qz = qp[2];
        float hq = 0.5f * fmaf(qx, qx, fmaf(qy, qy, qz * qz));
        unsigned short xh = bf16h(qx), xl = bf16h(qx - bf16tof(xh));
        unsigned short yh = bf16h(qy), yl = bf16h(qy - bf16tof(yh));
        unsigned short zh = bf16h(qz), zl = bf16h(qz - bf16tof(zh));
        unsigned short qh = bf16h(hq), ql = bf16h(hq - bf16tof(qh));
        bf16x8 a;
        if (half == 0) {
            a[0] = (short)xh; a[1] = (short)xh; a[2] = (short)xl;
            a[3] = (short)yh; a[4] = (short)yh; a[5] = (short)yl;
            a[6] = (short)zh; a[7] = (short)zh;
        } else {
            a[0] = (short)zl; a[1] = (short)qh; a[2] = (short)ql;
            a[3] = (short)one; a[4] = (short)one;
            a[5] = 0; a[6] = 0; a[7] = 0;
        }
        af[g] = a;
    }

    float rmn[NAF][16];
#pragma unroll
    for (int g = 0; g < NAF; g++)
#pragma unroll
        for (int r = 0; r < 16; r++) rmn[g][r] = 3.4e38f;
    const f32x16 zz = {};   // persistent zero VGPRs, C input for all MFMAs
    const uint4* Bh = half ? Bfr1 : Bfr0;

    const uint4* fb = FB + ((size_t)b * NPTS + (size_t)ds * DBR) * 2;

    // reg-stage chunk 0 (T14: issue early, write after barrier)
    uint4 r0 = fb[2 * tid + 0], r1 = fb[2 * tid + 1];

    for (int c = 0; c < NCH; ++c) {
        __syncthreads();                     // prev chunk's LDS reads done
        Bfr0[tid] = r0;
        Bfr1[tid] = r1;
        __syncthreads();                     // staging visible
        if (c + 1 < NCH) {                   // prefetch next chunk into regs
            r0 = fb[2 * ((c + 1) * CH + tid) + 0];
            r1 = fb[2 * ((c + 1) * CH + tid) + 1];
        }

#pragma unroll 2
        for (int tp = 0; tp < CH / 64; ++tp) {   // 4 tile-pairs of 64 db pts
            const int t0 = tp * 2, t1 = tp * 2 + 1;
            bf16x8 b0 = *reinterpret_cast<const bf16x8*>(&Bh[t0 * 32 + l31]);
            bf16x8 b1 = *reinterpret_cast<const bf16x8*>(&Bh[t1 * 32 + l31]);

            // region 1: batch-1 issue (4 MFMAs in flight, distinct dests)
            f32x16 a00 = __builtin_amdgcn_mfma_f32_32x32x16_bf16(af[0], b0, zz, 0, 0, 0);
            f32x16 a01 = __builtin_amdgcn_mfma_f32_32x32x16_bf16(af[0], b1, zz, 0, 0, 0);
            f32x16 a10 = __builtin_amdgcn_mfma_f32_32x32x16_bf16(af[1], b0, zz, 0, 0, 0);
            f32x16 a11 = __builtin_amdgcn_mfma_f32_32x32x16_bf16(af[1], b1, zz, 0, 0, 0);
            __builtin_amdgcn_sched_barrier(0);

            // region 2: batch-2 issue + batch-1 consume (interleaved)
            f32x16 a20 = __builtin_amdgcn_mfma_f32_32x32x16_bf16(af[2], b0, zz, 0, 0, 0);
            f32x16 a21 = __builtin_amdgcn_mfma_f32_32x32x16_bf16(af[2], b1, zz, 0, 0, 0);
            f32x16 a30 = __builtin_amdgcn_mfma_f32_32x32x16_bf16(af[3], b0, zz, 0, 0, 0);
            f32x16 a31 = __builtin_amdgcn_mfma_f32_32x32x16_bf16(af[3], b1, zz, 0, 0, 0);
#pragma unroll
            for (int r = 0; r < 16; r++)
                rmn[0][r] = fmin3(rmn[0][r], a00[r], a01[r]);
#pragma unroll
            for (int r = 0; r < 16; r++)
                rmn[1][r] = fmin3(rmn[1][r], a10[r], a11[r]);
            __builtin_amdgcn_sched_barrier(0);

            // region 3: batch-2 consume
#pragma unroll
            for (int r = 0; r < 16; r++)
                rmn[2][r] = fmin3(rmn[2][r], a20[r], a21[r]);
#pragma unroll
            for (int r = 0; r < 16; r++)
                rmn[3][r] = fmin3(rmn[3][r], a30[r], a31[r]);
        }
    }

    // ---- epilogue: fold cols 32->1 in-wave, global atomicMin merge ----
    unsigned int* M = mins + ((size_t)dir * BATCH + b) * NPTS;
    const int qbase = qb * QTILE + w * (32 * NAF);
#pragma unroll
    for (int g = 0; g < NAF; g++) {
#pragma unroll
        for (int r = 0; r < 16; r++) {
            float a = rmn[g][r];
#pragma unroll
            for (int off = 16; off > 0; off >>= 1)
                a = fminf(a, __shfl_xor(a, off, 64));
            if (l31 == 0) {   // lanes 0 (half0 row) and 32 (half1 row)
                const int row = (r & 3) + 8 * (r >> 2) + 4 * half;
                atomicMin(&M[qbase + g * 32 + row],
                          __float_as_uint(fmaxf(a, 0.0f)));
            }
        }
    }
}

// ---- final: sum mins[2][B][NPTS] (512KB), atomicAdd into out ----
__global__ __launch_bounds__(BLOCK) void chamfer_final(
    const unsigned int* __restrict__ mins, float* __restrict__ out)
{
    const int seg = blockIdx.x;   // 4 segments of 2048
    const int b   = blockIdx.y;
    const int tid = threadIdx.x;
    float acc = 0.0f;
#pragma unroll
    for (int k = 0; k < 8; k++) {
        const size_t i = (size_t)b * NPTS + seg * 2048 + k * BLOCK + tid;
        acc += __uint_as_float(mins[i]) + __uint_as_float(mins[SM_N + i]);
    }
    for (int off = 32; off > 0; off >>= 1) acc += __shfl_down(acc, off, 64);
    __shared__ float wsum[4];
    if ((tid & 63) == 0) wsum[tid >> 6] = acc;
    __syncthreads();
    if (tid == 0)   // stored values are half-distances: d = 2h
        atomicAdd(&out[b],
                  (wsum[0] + wsum[1] + wsum[2] + wsum[3]) * (2.0f / (float)NPTS));
}

extern "C" void kernel_launch(void* const* d_in, const int* in_sizes, int n_in,
                              void* d_out, int out_size, void* d_ws, size_t ws_size,
                              hipStream_t stream) {
    const float* src = (const float*)d_in[0];  // [B, N, 3]
    const float* tgt = (const float*)d_in[1];  // [B, M, 3]
    float* out = (float*)d_out;                // [B]

    uint4* fragT        = (uint4*)d_ws;                     // 2 MB
    uint4* fragS        = fragT + FRAG_N;                   // 2 MB
    unsigned int* mins  = (unsigned int*)(fragS + FRAG_N);  // 512 KB

    chamfer_prep<<<BATCH * NPTS / BLOCK, BLOCK, 0, stream>>>(
        src, tgt, fragS, fragT, mins, out);
    chamfer_nn<<<NBLK, BLOCK, 0, stream>>>(
        src, tgt, fragS, fragT, mins);
    chamfer_final<<<dim3(4, BATCH), BLOCK, 0, stream>>>(mins, out);
}